// Round 1
// baseline (18012.224 us; speedup 1.0000x reference)
//
#include <hip/hip_runtime.h>
#include <cstdint>
#include <cstddef>

#define B_GRAPHS 32
#define NPG      8192
#define N_NODES  (B_GRAPHS * NPG)   // 262144
#define DEG      8
#define NE       (N_NODES * DEG)    // 2097152
#define N1       32768              // B * 32*32  (grid 4)
#define N2       8192               // B * 16*16  (grid 8)

// ---------------------------------------------------------------------------
// Edge conv: msg = relu([h[src], pos2[src]-pos2[dst]] @ W + b), max-scatter to dst.
// All outputs >= 0, so atomicMax on int bit pattern with 0-init == segment_max + finite->0.
// ---------------------------------------------------------------------------
template<int IN_H, int OUT>
__global__ __launch_bounds__(256)
void conv_kernel(const float* __restrict__ h, const float* __restrict__ pos,
                 const int* __restrict__ src, const int* __restrict__ dst,
                 const float* __restrict__ W, const float* __restrict__ bias,
                 float* __restrict__ out, int nE, int nNodes) {
    constexpr int FEAT = IN_H + 2;
    __shared__ float Ws[FEAT * OUT + OUT];
    for (int i = threadIdx.x; i < FEAT * OUT; i += 256) Ws[i] = W[i];
    for (int i = threadIdx.x; i < OUT; i += 256) Ws[FEAT * OUT + i] = bias[i];
    __syncthreads();

    int e = blockIdx.x * 256 + threadIdx.x;
    if (e >= nE) return;
    int d = dst[e];
    if ((unsigned)d >= (unsigned)nNodes) return;   // sentinel / dropped edge
    int s = src[e];

    float acc[OUT];
    #pragma unroll
    for (int o = 0; o < OUT; ++o) acc[o] = Ws[FEAT * OUT + o];

    float dpx = pos[s * 3 + 0] - pos[d * 3 + 0];
    float dpy = pos[s * 3 + 1] - pos[d * 3 + 1];
    #pragma unroll
    for (int o = 0; o < OUT; ++o)
        acc[o] += dpx * Ws[IN_H * OUT + o] + dpy * Ws[(IN_H + 1) * OUT + o];

    if constexpr (IN_H % 4 == 0) {
        const float4* h4 = (const float4*)(h + (size_t)s * IN_H);
        for (int k4 = 0; k4 < IN_H / 4; ++k4) {
            float4 f = h4[k4];
            #pragma unroll
            for (int o = 0; o < OUT; ++o) {
                acc[o] += f.x * Ws[(k4 * 4 + 0) * OUT + o];
                acc[o] += f.y * Ws[(k4 * 4 + 1) * OUT + o];
                acc[o] += f.z * Ws[(k4 * 4 + 2) * OUT + o];
                acc[o] += f.w * Ws[(k4 * 4 + 3) * OUT + o];
            }
        }
    } else {
        for (int k = 0; k < IN_H; ++k) {
            float f = h[(size_t)s * IN_H + k];
            #pragma unroll
            for (int o = 0; o < OUT; ++o) acc[o] += f * Ws[k * OUT + o];
        }
    }

    int* op = (int*)(out + (size_t)d * OUT);
    #pragma unroll
    for (int o = 0; o < OUT; ++o)
        atomicMax(op + o, __float_as_int(fmaxf(acc[o], 0.0f)));
}

// ---------------------------------------------------------------------------
// Voxel pool: cluster id, max-pool h, sum pos + count (for mean).
// ---------------------------------------------------------------------------
template<int CH>
__global__ __launch_bounds__(256)
void pool_kernel(const float* __restrict__ h, const float* __restrict__ pos,
                 int* __restrict__ cluster, float* __restrict__ h_new,
                 float* __restrict__ pos_sum, float* __restrict__ cnt,
                 int n_old, int batch_shift, float inv_grid, int cells) {
    int i = blockIdx.x * 256 + threadIdx.x;
    if (i >= n_old) return;
    float px = pos[i * 3 + 0], py = pos[i * 3 + 1], pz = pos[i * 3 + 2];
    int ix = min(max((int)floorf(px * inv_grid), 0), cells - 1);
    int iy = min(max((int)floorf(py * inv_grid), 0), cells - 1);
    int c = (i >> batch_shift) * cells * cells + iy * cells + ix;
    cluster[i] = c;
    #pragma unroll 4
    for (int ch = 0; ch < CH; ++ch)
        atomicMax((int*)&h_new[(size_t)c * CH + ch], __float_as_int(h[(size_t)i * CH + ch]));
    atomicAdd(&pos_sum[c * 3 + 0], px);
    atomicAdd(&pos_sum[c * 3 + 1], py);
    atomicAdd(&pos_sum[c * 3 + 2], pz);
    atomicAdd(&cnt[c], 1.0f);
}

__global__ __launch_bounds__(256)
void posfin_kernel(const float* __restrict__ pos_sum, const float* __restrict__ cnt,
                   float* __restrict__ pos_new, int n_new) {
    int i = blockIdx.x * 256 + threadIdx.x;
    if (i >= n_new) return;
    float c = fmaxf(cnt[i], 1.0f);
    pos_new[i * 3 + 0] = pos_sum[i * 3 + 0] / c;
    pos_new[i * 3 + 1] = pos_sum[i * 3 + 1] / c;
    pos_new[i * 3 + 2] = pos_sum[i * 3 + 2] / c;
}

__global__ __launch_bounds__(256)
void remap_kernel(const int* __restrict__ src, const int* __restrict__ dst,
                  const int* __restrict__ cluster, int* __restrict__ src_new,
                  int* __restrict__ dst_new, int nE, int n_old, int sentinel) {
    int e = blockIdx.x * 256 + threadIdx.x;
    if (e >= nE) return;
    int s = src[e], d = dst[e];
    int sn = cluster[s];
    int dn = (d < n_old) ? cluster[d] : sentinel;
    if (sn == dn) dn = sentinel;          // drop self-loops
    src_new[e] = sn;
    dst_new[e] = dn;
}

// ---------------------------------------------------------------------------
// Fixed 8x8 grid output pool over final nodes (h >= 0, g zero-initialized).
// ---------------------------------------------------------------------------
__global__ __launch_bounds__(256)
void pool_out_kernel(const float* __restrict__ h, const float* __restrict__ pos,
                     float* __restrict__ g) {
    int i = blockIdx.x * 256 + threadIdx.x;
    if (i >= N2) return;
    float px = pos[i * 3 + 0], py = pos[i * 3 + 1];
    int ix = min(max((int)floorf(px * (1.0f / 16.0f)), 0), 7);
    int iy = min(max((int)floorf(py * (1.0f / 16.0f)), 0), 7);
    int cell = (i >> 8) * 64 + iy * 8 + ix;
    int* gp = (int*)(g + (size_t)cell * 64);
    #pragma unroll 8
    for (int ch = 0; ch < 64; ++ch)
        atomicMax(gp + ch, __float_as_int(h[(size_t)i * 64 + ch]));
}

// ---------------------------------------------------------------------------
// MLP head. mlp1: hid[b,o] += sum_k g[b,k]*Wl1[k,o] (split-K over blockIdx.y).
// ---------------------------------------------------------------------------
__global__ __launch_bounds__(256)
void mlp1_kernel(const float* __restrict__ g, const float* __restrict__ Wl1,
                 float* __restrict__ hid) {
    int b = blockIdx.x, kc = blockIdx.y, t = threadIdx.x;
    const float* grow = g + (size_t)b * 4096;
    int o0 = t * 4;
    float a0 = 0, a1 = 0, a2 = 0, a3 = 0;
    int k0 = kc * 512;
    for (int k = k0; k < k0 + 512; ++k) {
        float gk = grow[k];
        float4 w = *(const float4*)&Wl1[(size_t)k * 1024 + o0];
        a0 += gk * w.x; a1 += gk * w.y; a2 += gk * w.z; a3 += gk * w.w;
    }
    float* hp = hid + (size_t)b * 1024 + o0;
    atomicAdd(hp + 0, a0);
    atomicAdd(hp + 1, a1);
    atomicAdd(hp + 2, a2);
    atomicAdd(hp + 3, a3);
}

__global__ __launch_bounds__(64)
void mlp2_kernel(const float* __restrict__ hid, const float* __restrict__ bl1,
                 const float* __restrict__ Wl2, const float* __restrict__ bl2,
                 float* __restrict__ out) {
    int b = blockIdx.x, l = threadIdx.x;
    float hv[16];
    #pragma unroll
    for (int i = 0; i < 16; ++i) {
        int idx = l + i * 64;
        hv[i] = fmaxf(hid[(size_t)b * 1024 + idx] + bl1[idx], 0.0f);
    }
    float logits[10];
    #pragma unroll
    for (int c = 0; c < 10; ++c) {
        float p = 0.0f;
        #pragma unroll
        for (int i = 0; i < 16; ++i)
            p += hv[i] * Wl2[(size_t)(l + i * 64) * 10 + c];
        #pragma unroll
        for (int off = 32; off > 0; off >>= 1) p += __shfl_xor(p, off, 64);
        logits[c] = p + bl2[c];
    }
    float m = logits[0];
    #pragma unroll
    for (int c = 1; c < 10; ++c) m = fmaxf(m, logits[c]);
    float ssum = 0.0f;
    #pragma unroll
    for (int c = 0; c < 10; ++c) ssum += expf(logits[c] - m);
    float lse = logf(ssum);
    if (l < 10) out[b * 10 + l] = logits[l] - m - lse;
}

// ---------------------------------------------------------------------------
extern "C" void kernel_launch(void* const* d_in, const int* in_sizes, int n_in,
                              void* d_out, int out_size, void* d_ws, size_t ws_size,
                              hipStream_t stream) {
    const float* x    = (const float*)d_in[0];
    const float* pos0 = (const float*)d_in[1];
    const int*   ei   = (const int*)d_in[2];
    const float* W1 = (const float*)d_in[4];  const float* b1 = (const float*)d_in[5];
    const float* W2 = (const float*)d_in[6];  const float* b2 = (const float*)d_in[7];
    const float* W3 = (const float*)d_in[8];  const float* b3 = (const float*)d_in[9];
    const float* W4 = (const float*)d_in[10]; const float* b4 = (const float*)d_in[11];
    const float* W5 = (const float*)d_in[12]; const float* b5 = (const float*)d_in[13];
    const float* Wl1 = (const float*)d_in[14]; const float* bl1 = (const float*)d_in[15];
    const float* Wl2 = (const float*)d_in[16]; const float* bl2 = (const float*)d_in[17];
    const int* src0 = ei;
    const int* dst0 = ei + NE;
    float* out = (float*)d_out;

    float* w = (float*)d_ws;
    size_t off = 0;
    auto alloc = [&](size_t n) { float* p = w + off; off += n; return p; };

    // --- zero-init region (accumulators), contiguous so one memset covers it ---
    float* h1    = alloc((size_t)N_NODES * 16);
    float* hp1   = alloc((size_t)N1 * 16);
    float* psum1 = alloc((size_t)N1 * 3);
    float* cnt1  = alloc(N1);
    float* h2    = alloc((size_t)N1 * 32);
    float* h3    = alloc((size_t)N1 * 32);
    float* hp2   = alloc((size_t)N2 * 32);
    float* psum2 = alloc((size_t)N2 * 3);
    float* cnt2  = alloc(N2);
    float* h4    = alloc((size_t)N2 * 64);
    float* h5    = alloc((size_t)N2 * 64);
    float* g     = alloc((size_t)B_GRAPHS * 4096);
    float* hid   = alloc((size_t)B_GRAPHS * 1024);
    size_t zero_bytes = off * sizeof(float);
    // --- fully-overwritten region ---
    int*   c1   = (int*)alloc(N_NODES);
    int*   s1   = (int*)alloc(NE);
    int*   d1   = (int*)alloc(NE);
    float* pos1 = alloc((size_t)N1 * 3);
    int*   c2   = (int*)alloc(N1);
    int*   s2   = (int*)alloc(NE);
    int*   d2   = (int*)alloc(NE);
    float* pos2 = alloc((size_t)N2 * 3);
    (void)ws_size; (void)in_sizes; (void)n_in; (void)out_size;

    hipMemsetAsync(d_ws, 0, zero_bytes, stream);

    const int eblocks = NE / 256;
    // stage 1: conv1 on raw events
    conv_kernel<1, 16><<<eblocks, 256, 0, stream>>>(x, pos0, src0, dst0, W1, b1, h1, NE, N_NODES);
    // voxel pool grid=4 (cells=32)
    pool_kernel<16><<<N_NODES / 256, 256, 0, stream>>>(h1, pos0, c1, hp1, psum1, cnt1,
                                                       N_NODES, 13, 0.25f, 32);
    posfin_kernel<<<N1 / 256, 256, 0, stream>>>(psum1, cnt1, pos1, N1);
    remap_kernel<<<eblocks, 256, 0, stream>>>(src0, dst0, c1, s1, d1, NE, N_NODES, N1);
    // conv2, conv3 on n1 clusters
    conv_kernel<16, 32><<<eblocks, 256, 0, stream>>>(hp1, pos1, s1, d1, W2, b2, h2, NE, N1);
    conv_kernel<32, 32><<<eblocks, 256, 0, stream>>>(h2, pos1, s1, d1, W3, b3, h3, NE, N1);
    // voxel pool grid=8 (cells=16)
    pool_kernel<32><<<N1 / 256, 256, 0, stream>>>(h3, pos1, c2, hp2, psum2, cnt2,
                                                  N1, 10, 0.125f, 16);
    posfin_kernel<<<N2 / 256, 256, 0, stream>>>(psum2, cnt2, pos2, N2);
    remap_kernel<<<eblocks, 256, 0, stream>>>(s1, d1, c2, s2, d2, NE, N1, N2);
    // conv4, conv5 on n2 clusters
    conv_kernel<32, 64><<<eblocks, 256, 0, stream>>>(hp2, pos2, s2, d2, W4, b4, h4, NE, N2);
    conv_kernel<64, 64><<<eblocks, 256, 0, stream>>>(h4, pos2, s2, d2, W5, b5, h5, NE, N2);
    // fixed 8x8 output pool -> g[32, 4096]
    pool_out_kernel<<<N2 / 256, 256, 0, stream>>>(h5, pos2, g);
    // MLP head
    mlp1_kernel<<<dim3(32, 8), 256, 0, stream>>>(g, Wl1, hid);
    mlp2_kernel<<<32, 64, 0, stream>>>(hid, bl1, Wl2, bl2, out);
}

// Round 2
// 1942.188 us; speedup vs baseline: 9.2742x; 9.2742x over previous
//
#include <hip/hip_runtime.h>
#include <cstdint>
#include <cstddef>

#define B_GRAPHS 32
#define NPG      8192
#define N_NODES  (B_GRAPHS * NPG)   // 262144
#define DEG      8
#define NE       (N_NODES * DEG)    // 2097152
#define N1       32768              // B * 32*32  (grid 4)
#define N2       8192               // B * 16*16  (grid 8)

// ---------------------------------------------------------------------------
// Node-level precompute: a[i,o] = b[o] + sum_k h[i,k]*W[k,o] + px*W[IN,o] + py*W[IN+1,o]
// (the per-edge message is then a[src,o] - (px_d*W[IN,o] + py_d*W[IN+1,o]), relu'd)
// ---------------------------------------------------------------------------
template<int IN, int OUT>
__global__ __launch_bounds__(256)
void node_a_kernel(const float* __restrict__ h, const float* __restrict__ pos,
                   const float* __restrict__ W, const float* __restrict__ bias,
                   float* __restrict__ a, int n) {
    constexpr int FEAT = IN + 2;
    __shared__ float Ws[FEAT * OUT + OUT];
    for (int i = threadIdx.x; i < FEAT * OUT; i += 256) Ws[i] = W[i];
    for (int i = threadIdx.x; i < OUT; i += 256) Ws[FEAT * OUT + i] = bias[i];
    __syncthreads();
    int i = blockIdx.x * 256 + threadIdx.x;
    if (i >= n) return;

    float acc[OUT];
    #pragma unroll
    for (int o = 0; o < OUT; ++o) acc[o] = Ws[FEAT * OUT + o];

    float px = pos[i * 3 + 0], py = pos[i * 3 + 1];
    #pragma unroll
    for (int o = 0; o < OUT; ++o)
        acc[o] += px * Ws[IN * OUT + o] + py * Ws[(IN + 1) * OUT + o];

    if constexpr (IN % 4 == 0) {
        const float4* h4 = (const float4*)(h + (size_t)i * IN);
        for (int k4 = 0; k4 < IN / 4; ++k4) {
            float4 f = h4[k4];
            #pragma unroll
            for (int o = 0; o < OUT; ++o) {
                acc[o] += f.x * Ws[(k4 * 4 + 0) * OUT + o];
                acc[o] += f.y * Ws[(k4 * 4 + 1) * OUT + o];
                acc[o] += f.z * Ws[(k4 * 4 + 2) * OUT + o];
                acc[o] += f.w * Ws[(k4 * 4 + 3) * OUT + o];
            }
        }
    } else {
        for (int k = 0; k < IN; ++k) {
            float f = h[(size_t)i * IN + k];
            #pragma unroll
            for (int o = 0; o < OUT; ++o) acc[o] += f * Ws[k * OUT + o];
        }
    }
    float* ap = a + (size_t)i * OUT;
    #pragma unroll
    for (int o = 0; o < OUT; ++o) ap[o] = acc[o];
}

// ---------------------------------------------------------------------------
// CSR build: counts -> scan -> fill
// ---------------------------------------------------------------------------
__global__ __launch_bounds__(256)
void count_kernel(const int* __restrict__ dst, int* __restrict__ counts, int nE, int n) {
    int e = blockIdx.x * 256 + threadIdx.x;
    if (e >= nE) return;
    int d = dst[e];
    if ((unsigned)d < (unsigned)n) atomicAdd(&counts[d], 1);
}

__global__ __launch_bounds__(1024)
void scan_kernel(const int* __restrict__ counts, int* __restrict__ offsets,
                 int* __restrict__ cursor, int n) {
    __shared__ int part[1024];
    int t = threadIdx.x;
    int C = (n + 1023) >> 10;
    int base = t * C;
    int lim = min(C, n - base); if (lim < 0) lim = 0;
    int s = 0;
    for (int i = 0; i < lim; ++i) s += counts[base + i];
    part[t] = s;
    __syncthreads();
    for (int d = 1; d < 1024; d <<= 1) {
        int v = (t >= d) ? part[t - d] : 0;
        __syncthreads();
        part[t] += v;
        __syncthreads();
    }
    int run = (t == 0) ? 0 : part[t - 1];
    for (int i = 0; i < lim; ++i) {
        offsets[base + i] = run;
        cursor[base + i] = run;
        run += counts[base + i];
    }
    if (t == 1023) offsets[n] = part[1023];
}

__global__ __launch_bounds__(256)
void fill_kernel(const int* __restrict__ src, const int* __restrict__ dst,
                 int* __restrict__ cursor, int* __restrict__ csr_src, int nE, int n) {
    int e = blockIdx.x * 256 + threadIdx.x;
    if (e >= nE) return;
    int d = dst[e];
    if ((unsigned)d >= (unsigned)n) return;
    int p = atomicAdd(&cursor[d], 1);
    csr_src[p] = src[e];
}

// ---------------------------------------------------------------------------
// Gather-max conv: one wave per dst node. lane = g*OUT + ch; group g strides edges.
// Wp points at W row IN (the 2 pos-delta rows). MODE 0: store; MODE 1: atomicMax
// into pool[cluster[dst]] (values >= 0, buffer zero-initialized).
// ---------------------------------------------------------------------------
template<int OUT, int MODE>
__global__ __launch_bounds__(256)
void gather_kernel(const float* __restrict__ a, const float* __restrict__ pos,
                   const float* __restrict__ Wp,
                   const int* __restrict__ offsets, const int* __restrict__ csr_src,
                   const int* __restrict__ cluster,
                   float* __restrict__ out, int n) {
    constexpr int G = 64 / OUT;
    int wave = (blockIdx.x * 256 + threadIdx.x) >> 6;
    int lane = threadIdx.x & 63;
    int ch = lane % OUT, g = lane / OUT;
    if (wave >= n) return;
    int off = offsets[wave], end = offsets[wave + 1];
    float m = -1e30f;
    for (int j = off + g; j < end; j += G) {
        int s = csr_src[j];
        m = fmaxf(m, a[(size_t)s * OUT + ch]);
    }
    #pragma unroll
    for (int st = OUT; st < 64; st <<= 1)
        m = fmaxf(m, __shfl_xor(m, st, 64));
    float px = pos[wave * 3 + 0], py = pos[wave * 3 + 1];
    float cterm = px * Wp[ch] + py * Wp[OUT + ch];
    float val = (end > off) ? fmaxf(m - cterm, 0.0f) : 0.0f;
    if (g == 0) {
        if (MODE == 0) {
            out[(size_t)wave * OUT + ch] = val;
        } else if (val > 0.0f) {
            atomicMax((int*)&out[(size_t)cluster[wave] * OUT + ch], __float_as_int(val));
        }
    }
}

// ---------------------------------------------------------------------------
// Voxel cluster id + pos mean accumulation
// ---------------------------------------------------------------------------
__global__ __launch_bounds__(256)
void cluster_kernel(const float* __restrict__ pos, int* __restrict__ cluster,
                    float* __restrict__ psum, float* __restrict__ cnt,
                    int n, int batch_shift, float inv_grid, int cells) {
    int i = blockIdx.x * 256 + threadIdx.x;
    if (i >= n) return;
    float px = pos[i * 3 + 0], py = pos[i * 3 + 1], pz = pos[i * 3 + 2];
    int ix = min(max((int)floorf(px * inv_grid), 0), cells - 1);
    int iy = min(max((int)floorf(py * inv_grid), 0), cells - 1);
    int c = (i >> batch_shift) * cells * cells + iy * cells + ix;
    cluster[i] = c;
    atomicAdd(&psum[c * 3 + 0], px);
    atomicAdd(&psum[c * 3 + 1], py);
    atomicAdd(&psum[c * 3 + 2], pz);
    atomicAdd(&cnt[c], 1.0f);
}

__global__ __launch_bounds__(256)
void cellout_kernel(const float* __restrict__ pos, int* __restrict__ cell, int n) {
    int i = blockIdx.x * 256 + threadIdx.x;
    if (i >= n) return;
    float px = pos[i * 3 + 0], py = pos[i * 3 + 1];
    int ix = min(max((int)floorf(px * (1.0f / 16.0f)), 0), 7);
    int iy = min(max((int)floorf(py * (1.0f / 16.0f)), 0), 7);
    cell[i] = (i >> 8) * 64 + iy * 8 + ix;
}

__global__ __launch_bounds__(256)
void posfin_kernel(const float* __restrict__ pos_sum, const float* __restrict__ cnt,
                   float* __restrict__ pos_new, int n_new) {
    int i = blockIdx.x * 256 + threadIdx.x;
    if (i >= n_new) return;
    float c = fmaxf(cnt[i], 1.0f);
    pos_new[i * 3 + 0] = pos_sum[i * 3 + 0] / c;
    pos_new[i * 3 + 1] = pos_sum[i * 3 + 1] / c;
    pos_new[i * 3 + 2] = pos_sum[i * 3 + 2] / c;
}

__global__ __launch_bounds__(256)
void remap_kernel(const int* __restrict__ src, const int* __restrict__ dst,
                  const int* __restrict__ cluster, int* __restrict__ src_new,
                  int* __restrict__ dst_new, int nE, int n_old, int sentinel) {
    int e = blockIdx.x * 256 + threadIdx.x;
    if (e >= nE) return;
    int s = src[e], d = dst[e];
    int sn = cluster[s];
    int dn = ((unsigned)d < (unsigned)n_old) ? cluster[d] : sentinel;
    if (sn == dn) dn = sentinel;
    src_new[e] = sn;
    dst_new[e] = dn;
}

// ---------------------------------------------------------------------------
// MLP head
// ---------------------------------------------------------------------------
__global__ __launch_bounds__(256)
void mlp1_kernel(const float* __restrict__ g, const float* __restrict__ Wl1,
                 float* __restrict__ hid) {
    int b = blockIdx.x, kc = blockIdx.y, t = threadIdx.x;
    const float* grow = g + (size_t)b * 4096;
    int o0 = t * 4;
    float a0 = 0, a1 = 0, a2 = 0, a3 = 0;
    int k0 = kc * 512;
    for (int k = k0; k < k0 + 512; ++k) {
        float gk = grow[k];
        float4 w = *(const float4*)&Wl1[(size_t)k * 1024 + o0];
        a0 += gk * w.x; a1 += gk * w.y; a2 += gk * w.z; a3 += gk * w.w;
    }
    float* hp = hid + (size_t)b * 1024 + o0;
    atomicAdd(hp + 0, a0);
    atomicAdd(hp + 1, a1);
    atomicAdd(hp + 2, a2);
    atomicAdd(hp + 3, a3);
}

__global__ __launch_bounds__(64)
void mlp2_kernel(const float* __restrict__ hid, const float* __restrict__ bl1,
                 const float* __restrict__ Wl2, const float* __restrict__ bl2,
                 float* __restrict__ out) {
    int b = blockIdx.x, l = threadIdx.x;
    float hv[16];
    #pragma unroll
    for (int i = 0; i < 16; ++i) {
        int idx = l + i * 64;
        hv[i] = fmaxf(hid[(size_t)b * 1024 + idx] + bl1[idx], 0.0f);
    }
    float logits[10];
    #pragma unroll
    for (int c = 0; c < 10; ++c) {
        float p = 0.0f;
        #pragma unroll
        for (int i = 0; i < 16; ++i)
            p += hv[i] * Wl2[(size_t)(l + i * 64) * 10 + c];
        #pragma unroll
        for (int off = 32; off > 0; off >>= 1) p += __shfl_xor(p, off, 64);
        logits[c] = p + bl2[c];
    }
    float m = logits[0];
    #pragma unroll
    for (int c = 1; c < 10; ++c) m = fmaxf(m, logits[c]);
    float ssum = 0.0f;
    #pragma unroll
    for (int c = 0; c < 10; ++c) ssum += expf(logits[c] - m);
    float lse = logf(ssum);
    if (l < 10) out[b * 10 + l] = logits[l] - m - lse;
}

// ---------------------------------------------------------------------------
extern "C" void kernel_launch(void* const* d_in, const int* in_sizes, int n_in,
                              void* d_out, int out_size, void* d_ws, size_t ws_size,
                              hipStream_t stream) {
    const float* x    = (const float*)d_in[0];
    const float* pos0 = (const float*)d_in[1];
    const int*   ei   = (const int*)d_in[2];
    const float* W1 = (const float*)d_in[4];  const float* b1 = (const float*)d_in[5];
    const float* W2 = (const float*)d_in[6];  const float* b2 = (const float*)d_in[7];
    const float* W3 = (const float*)d_in[8];  const float* b3 = (const float*)d_in[9];
    const float* W4 = (const float*)d_in[10]; const float* b4 = (const float*)d_in[11];
    const float* W5 = (const float*)d_in[12]; const float* b5 = (const float*)d_in[13];
    const float* Wl1 = (const float*)d_in[14]; const float* bl1 = (const float*)d_in[15];
    const float* Wl2 = (const float*)d_in[16]; const float* bl2 = (const float*)d_in[17];
    const int* src0 = ei;
    const int* dst0 = ei + NE;
    float* out = (float*)d_out;

    float* w = (float*)d_ws;
    size_t off = 0;
    auto alloc = [&](size_t n) { float* p = w + off; off += n; return p; };

    // --- zero-init region (pool accumulators), contiguous: one memset ---
    float* hp1   = alloc((size_t)N1 * 16);
    float* psum1 = alloc((size_t)N1 * 3);
    float* cnt1  = alloc(N1);
    float* hp2   = alloc((size_t)N2 * 32);
    float* psum2 = alloc((size_t)N2 * 3);
    float* cnt2  = alloc(N2);
    float* g     = alloc((size_t)B_GRAPHS * 4096);
    float* hid   = alloc((size_t)B_GRAPHS * 1024);
    size_t zero_bytes = off * sizeof(float);
    // --- rest (fully overwritten by kernels before use) ---
    float* abuf = alloc((size_t)N_NODES * 16);     // reused for all levels' a
    float* h2   = alloc((size_t)N1 * 32);
    float* h4   = alloc((size_t)N2 * 64);
    float* pos1 = alloc((size_t)N1 * 3);
    float* pos2 = alloc((size_t)N2 * 3);
    int* c1     = (int*)alloc(N_NODES);
    int* c2     = (int*)alloc(N1);                 // also reused for pool_out cells
    int* s1     = (int*)alloc(NE);
    int* d1     = (int*)alloc(NE);
    int* counts  = (int*)alloc(N_NODES + 2);
    int* offsets = (int*)alloc(N_NODES + 2);
    int* cursor  = (int*)alloc(N_NODES + 2);
    int* csr_src = (int*)alloc(NE);
    (void)ws_size; (void)in_sizes; (void)n_in; (void)out_size;

    hipMemsetAsync(d_ws, 0, zero_bytes, stream);

    const int eblocks = NE / 256;

    // ===== level A: conv1 on raw events (all dst valid), fused pool1 h-max =====
    node_a_kernel<1, 16><<<N_NODES / 256, 256, 0, stream>>>(x, pos0, W1, b1, abuf, N_NODES);
    hipMemsetAsync(counts, 0, (N_NODES + 1) * sizeof(int), stream);
    count_kernel<<<eblocks, 256, 0, stream>>>(dst0, counts, NE, N_NODES);
    scan_kernel<<<1, 1024, 0, stream>>>(counts, offsets, cursor, N_NODES);
    fill_kernel<<<eblocks, 256, 0, stream>>>(src0, dst0, cursor, csr_src, NE, N_NODES);
    cluster_kernel<<<N_NODES / 256, 256, 0, stream>>>(pos0, c1, psum1, cnt1, N_NODES, 13, 0.25f, 32);
    gather_kernel<16, 1><<<N_NODES / 4, 256, 0, stream>>>(abuf, pos0, W1 + 1 * 16,
                                                          offsets, csr_src, c1, hp1, N_NODES);
    posfin_kernel<<<N1 / 256, 256, 0, stream>>>(psum1, cnt1, pos1, N1);
    remap_kernel<<<eblocks, 256, 0, stream>>>(src0, dst0, c1, s1, d1, NE, N_NODES, N1);

    // ===== level B: conv2 (store), conv3 (fused pool2 h-max) =====
    hipMemsetAsync(counts, 0, (N1 + 1) * sizeof(int), stream);
    count_kernel<<<eblocks, 256, 0, stream>>>(d1, counts, NE, N1);
    scan_kernel<<<1, 1024, 0, stream>>>(counts, offsets, cursor, N1);
    fill_kernel<<<eblocks, 256, 0, stream>>>(s1, d1, cursor, csr_src, NE, N1);
    node_a_kernel<16, 32><<<N1 / 256, 256, 0, stream>>>(hp1, pos1, W2, b2, abuf, N1);
    gather_kernel<32, 0><<<N1 / 4, 256, 0, stream>>>(abuf, pos1, W2 + 16 * 32,
                                                     offsets, csr_src, nullptr, h2, N1);
    node_a_kernel<32, 32><<<N1 / 256, 256, 0, stream>>>(h2, pos1, W3, b3, abuf, N1);
    cluster_kernel<<<N1 / 256, 256, 0, stream>>>(pos1, c2, psum2, cnt2, N1, 10, 0.125f, 16);
    gather_kernel<32, 1><<<N1 / 4, 256, 0, stream>>>(abuf, pos1, W3 + 32 * 32,
                                                     offsets, csr_src, c2, hp2, N1);
    posfin_kernel<<<N2 / 256, 256, 0, stream>>>(psum2, cnt2, pos2, N2);
    remap_kernel<<<eblocks, 256, 0, stream>>>(s1, d1, c2, s1, d1, NE, N1, N2);  // in-place

    // ===== level C: conv4 (store), conv5 (fused pool_out) =====
    hipMemsetAsync(counts, 0, (N2 + 1) * sizeof(int), stream);
    count_kernel<<<eblocks, 256, 0, stream>>>(d1, counts, NE, N2);
    scan_kernel<<<1, 1024, 0, stream>>>(counts, offsets, cursor, N2);
    fill_kernel<<<eblocks, 256, 0, stream>>>(s1, d1, cursor, csr_src, NE, N2);
    node_a_kernel<32, 64><<<N2 / 256, 256, 0, stream>>>(hp2, pos2, W4, b4, abuf, N2);
    gather_kernel<64, 0><<<N2 / 4, 256, 0, stream>>>(abuf, pos2, W4 + 32 * 64,
                                                     offsets, csr_src, nullptr, h4, N2);
    node_a_kernel<64, 64><<<N2 / 256, 256, 0, stream>>>(h4, pos2, W5, b5, abuf, N2);
    cellout_kernel<<<N2 / 256, 256, 0, stream>>>(pos2, c2, N2);
    gather_kernel<64, 1><<<N2 / 4, 256, 0, stream>>>(abuf, pos2, W5 + 64 * 64,
                                                     offsets, csr_src, c2, g, N2);

    // ===== MLP head =====
    mlp1_kernel<<<dim3(32, 8), 256, 0, stream>>>(g, Wl1, hid);
    mlp2_kernel<<<32, 64, 0, stream>>>(hid, bl1, Wl2, bl2, out);
}

// Round 3
// 1292.985 us; speedup vs baseline: 13.9307x; 1.5021x over previous
//
#include <hip/hip_runtime.h>
#include <cstdint>
#include <cstddef>

#define B_GRAPHS 32
#define NPG      8192
#define N_NODES  (B_GRAPHS * NPG)   // 262144
#define DEG      8
#define NE       (N_NODES * DEG)    // 2097152
#define N1       32768              // B * 32*32  (grid 4)
#define N2       8192               // B * 16*16  (grid 8)

// ---------------------------------------------------------------------------
// Node-level precompute: a[i,o] = b[o] + sum_k h[i,k]*W[k,o] + px*W[IN,o] + py*W[IN+1,o]
// ---------------------------------------------------------------------------
template<int IN, int OUT>
__global__ __launch_bounds__(256)
void node_a_kernel(const float* __restrict__ h, const float* __restrict__ pos,
                   const float* __restrict__ W, const float* __restrict__ bias,
                   float* __restrict__ a, int n) {
    constexpr int FEAT = IN + 2;
    __shared__ float Ws[FEAT * OUT + OUT];
    for (int i = threadIdx.x; i < FEAT * OUT; i += 256) Ws[i] = W[i];
    for (int i = threadIdx.x; i < OUT; i += 256) Ws[FEAT * OUT + i] = bias[i];
    __syncthreads();
    int i = blockIdx.x * 256 + threadIdx.x;
    if (i >= n) return;

    float acc[OUT];
    #pragma unroll
    for (int o = 0; o < OUT; ++o) acc[o] = Ws[FEAT * OUT + o];

    float px = pos[i * 3 + 0], py = pos[i * 3 + 1];
    #pragma unroll
    for (int o = 0; o < OUT; ++o)
        acc[o] += px * Ws[IN * OUT + o] + py * Ws[(IN + 1) * OUT + o];

    if constexpr (IN % 4 == 0) {
        const float4* h4 = (const float4*)(h + (size_t)i * IN);
        for (int k4 = 0; k4 < IN / 4; ++k4) {
            float4 f = h4[k4];
            #pragma unroll
            for (int o = 0; o < OUT; ++o) {
                acc[o] += f.x * Ws[(k4 * 4 + 0) * OUT + o];
                acc[o] += f.y * Ws[(k4 * 4 + 1) * OUT + o];
                acc[o] += f.z * Ws[(k4 * 4 + 2) * OUT + o];
                acc[o] += f.w * Ws[(k4 * 4 + 3) * OUT + o];
            }
        }
    } else {
        for (int k = 0; k < IN; ++k) {
            float f = h[(size_t)i * IN + k];
            #pragma unroll
            for (int o = 0; o < OUT; ++o) acc[o] += f * Ws[k * OUT + o];
        }
    }
    float* ap = a + (size_t)i * OUT;
    #pragma unroll
    for (int o = 0; o < OUT; ++o) ap[o] = acc[o];
}

// ---------------------------------------------------------------------------
// CSR build: count -> hierarchical scan (3 passes) -> fill.  n % 1024 == 0.
// ---------------------------------------------------------------------------
__global__ __launch_bounds__(256)
void count_kernel(const int* __restrict__ dst, int* __restrict__ counts, int nE, int n) {
    int e = blockIdx.x * 256 + threadIdx.x;
    if (e >= nE) return;
    int d = dst[e];
    if ((unsigned)d < (unsigned)n) atomicAdd(&counts[d], 1);
}

__global__ __launch_bounds__(256)
void scan_reduce_kernel(const int* __restrict__ counts, int* __restrict__ blocksums) {
    int t = threadIdx.x;
    int4 v = *(const int4*)&counts[blockIdx.x * 1024 + t * 4];
    int s = v.x + v.y + v.z + v.w;
    #pragma unroll
    for (int off = 32; off > 0; off >>= 1) s += __shfl_xor(s, off, 64);
    __shared__ int ws[4];
    if ((t & 63) == 0) ws[t >> 6] = s;
    __syncthreads();
    if (t == 0) blocksums[blockIdx.x] = ws[0] + ws[1] + ws[2] + ws[3];
}

__global__ __launch_bounds__(256)
void scan_blocks_kernel(const int* __restrict__ blocksums, int* __restrict__ blockpref,
                        int* __restrict__ offsets, int nb, int n) {
    __shared__ int sh[256];
    int t = threadIdx.x;
    int v = (t < nb) ? blocksums[t] : 0;
    sh[t] = v;
    __syncthreads();
    #pragma unroll
    for (int d = 1; d < 256; d <<= 1) {
        int u = (t >= d) ? sh[t - d] : 0;
        __syncthreads();
        sh[t] += u;
        __syncthreads();
    }
    if (t < nb) blockpref[t] = sh[t] - v;   // exclusive
    if (t == 255) offsets[n] = sh[255];
}

__global__ __launch_bounds__(256)
void scan_write_kernel(const int* __restrict__ counts, const int* __restrict__ blockpref,
                       int* __restrict__ offsets, int* __restrict__ cursor) {
    int b = blockIdx.x, t = threadIdx.x;
    int base = b * 1024 + t * 4;
    int4 v = *(const int4*)&counts[base];
    int s = v.x + v.y + v.z + v.w;
    __shared__ int sh[256];
    sh[t] = s;
    __syncthreads();
    #pragma unroll
    for (int d = 1; d < 256; d <<= 1) {
        int u = (t >= d) ? sh[t - d] : 0;
        __syncthreads();
        sh[t] += u;
        __syncthreads();
    }
    int pref = blockpref[b] + sh[t] - s;
    int4 o;
    o.x = pref;
    o.y = pref + v.x;
    o.z = o.y + v.y;
    o.w = o.z + v.z;
    *(int4*)&offsets[base] = o;
    *(int4*)&cursor[base] = o;
}

__global__ __launch_bounds__(256)
void fill_kernel(const int* __restrict__ src, const int* __restrict__ dst,
                 int* __restrict__ cursor, int* __restrict__ csr_src, int nE, int n) {
    int e = blockIdx.x * 256 + threadIdx.x;
    if (e >= nE) return;
    int d = dst[e];
    if ((unsigned)d >= (unsigned)n) return;
    int p = atomicAdd(&cursor[d], 1);
    csr_src[p] = src[e];
}

// ---------------------------------------------------------------------------
// Gather-max conv: one wave per dst node. lane = g*OUT + ch; group g strides edges.
// MODE 0: store; MODE 1: atomicMax into pool[cluster[dst]] (vals >= 0, 0-init).
// ---------------------------------------------------------------------------
template<int OUT, int MODE>
__global__ __launch_bounds__(256)
void gather_kernel(const float* __restrict__ a, const float* __restrict__ pos,
                   const float* __restrict__ Wp,
                   const int* __restrict__ offsets, const int* __restrict__ csr_src,
                   const int* __restrict__ cluster,
                   float* __restrict__ out, int n) {
    constexpr int G = 64 / OUT;
    int wave = (blockIdx.x * 256 + threadIdx.x) >> 6;
    int lane = threadIdx.x & 63;
    int ch = lane % OUT, g = lane / OUT;
    if (wave >= n) return;
    int off = offsets[wave], end = offsets[wave + 1];
    float m = -1e30f;
    for (int j = off + g; j < end; j += G) {
        int s = csr_src[j];
        m = fmaxf(m, a[(size_t)s * OUT + ch]);
    }
    #pragma unroll
    for (int st = OUT; st < 64; st <<= 1)
        m = fmaxf(m, __shfl_xor(m, st, 64));
    float px = pos[wave * 3 + 0], py = pos[wave * 3 + 1];
    float cterm = px * Wp[ch] + py * Wp[OUT + ch];
    float val = (end > off) ? fmaxf(m - cterm, 0.0f) : 0.0f;
    if (g == 0) {
        if (MODE == 0) {
            out[(size_t)wave * OUT + ch] = val;
        } else if (val > 0.0f) {
            atomicMax((int*)&out[(size_t)cluster[wave] * OUT + ch], __float_as_int(val));
        }
    }
}

// ---------------------------------------------------------------------------
// Voxel cluster id + pos mean accumulation
// ---------------------------------------------------------------------------
__global__ __launch_bounds__(256)
void cluster_kernel(const float* __restrict__ pos, int* __restrict__ cluster,
                    float* __restrict__ psum, float* __restrict__ cnt,
                    int n, int batch_shift, float inv_grid, int cells) {
    int i = blockIdx.x * 256 + threadIdx.x;
    if (i >= n) return;
    float px = pos[i * 3 + 0], py = pos[i * 3 + 1], pz = pos[i * 3 + 2];
    int ix = min(max((int)floorf(px * inv_grid), 0), cells - 1);
    int iy = min(max((int)floorf(py * inv_grid), 0), cells - 1);
    int c = (i >> batch_shift) * cells * cells + iy * cells + ix;
    cluster[i] = c;
    atomicAdd(&psum[c * 3 + 0], px);
    atomicAdd(&psum[c * 3 + 1], py);
    atomicAdd(&psum[c * 3 + 2], pz);
    atomicAdd(&cnt[c], 1.0f);
}

__global__ __launch_bounds__(256)
void cellout_kernel(const float* __restrict__ pos, int* __restrict__ cell, int n) {
    int i = blockIdx.x * 256 + threadIdx.x;
    if (i >= n) return;
    float px = pos[i * 3 + 0], py = pos[i * 3 + 1];
    int ix = min(max((int)floorf(px * (1.0f / 16.0f)), 0), 7);
    int iy = min(max((int)floorf(py * (1.0f / 16.0f)), 0), 7);
    cell[i] = (i >> 8) * 64 + iy * 8 + ix;
}

__global__ __launch_bounds__(256)
void posfin_kernel(const float* __restrict__ pos_sum, const float* __restrict__ cnt,
                   float* __restrict__ pos_new, int n_new) {
    int i = blockIdx.x * 256 + threadIdx.x;
    if (i >= n_new) return;
    float c = fmaxf(cnt[i], 1.0f);
    pos_new[i * 3 + 0] = pos_sum[i * 3 + 0] / c;
    pos_new[i * 3 + 1] = pos_sum[i * 3 + 1] / c;
    pos_new[i * 3 + 2] = pos_sum[i * 3 + 2] / c;
}

// remap + fused count of new destinations (counts must be pre-zeroed)
__global__ __launch_bounds__(256)
void remap_count_kernel(const int* __restrict__ src, const int* __restrict__ dst,
                        const int* __restrict__ cluster, int* __restrict__ src_new,
                        int* __restrict__ dst_new, int* __restrict__ counts,
                        int nE, int n_old, int sentinel) {
    int e = blockIdx.x * 256 + threadIdx.x;
    if (e >= nE) return;
    int s = src[e], d = dst[e];
    int sn = cluster[s];
    int dn = ((unsigned)d < (unsigned)n_old) ? cluster[d] : sentinel;
    if (sn == dn) dn = sentinel;
    src_new[e] = sn;
    dst_new[e] = dn;
    if (dn != sentinel) atomicAdd(&counts[dn], 1);
}

// ---------------------------------------------------------------------------
// MLP head
// ---------------------------------------------------------------------------
__global__ __launch_bounds__(256)
void mlp1_kernel(const float* __restrict__ g, const float* __restrict__ Wl1,
                 float* __restrict__ hid) {
    int b = blockIdx.x, kc = blockIdx.y, t = threadIdx.x;
    const float* grow = g + (size_t)b * 4096;
    int o0 = t * 4;
    float a0 = 0, a1 = 0, a2 = 0, a3 = 0;
    int k0 = kc * 512;
    for (int k = k0; k < k0 + 512; ++k) {
        float gk = grow[k];
        float4 w = *(const float4*)&Wl1[(size_t)k * 1024 + o0];
        a0 += gk * w.x; a1 += gk * w.y; a2 += gk * w.z; a3 += gk * w.w;
    }
    float* hp = hid + (size_t)b * 1024 + o0;
    atomicAdd(hp + 0, a0);
    atomicAdd(hp + 1, a1);
    atomicAdd(hp + 2, a2);
    atomicAdd(hp + 3, a3);
}

__global__ __launch_bounds__(64)
void mlp2_kernel(const float* __restrict__ hid, const float* __restrict__ bl1,
                 const float* __restrict__ Wl2, const float* __restrict__ bl2,
                 float* __restrict__ out) {
    int b = blockIdx.x, l = threadIdx.x;
    float hv[16];
    #pragma unroll
    for (int i = 0; i < 16; ++i) {
        int idx = l + i * 64;
        hv[i] = fmaxf(hid[(size_t)b * 1024 + idx] + bl1[idx], 0.0f);
    }
    float logits[10];
    #pragma unroll
    for (int c = 0; c < 10; ++c) {
        float p = 0.0f;
        #pragma unroll
        for (int i = 0; i < 16; ++i)
            p += hv[i] * Wl2[(size_t)(l + i * 64) * 10 + c];
        #pragma unroll
        for (int off = 32; off > 0; off >>= 1) p += __shfl_xor(p, off, 64);
        logits[c] = p + bl2[c];
    }
    float m = logits[0];
    #pragma unroll
    for (int c = 1; c < 10; ++c) m = fmaxf(m, logits[c]);
    float ssum = 0.0f;
    #pragma unroll
    for (int c = 0; c < 10; ++c) ssum += expf(logits[c] - m);
    float lse = logf(ssum);
    if (l < 10) out[b * 10 + l] = logits[l] - m - lse;
}

// ---------------------------------------------------------------------------
extern "C" void kernel_launch(void* const* d_in, const int* in_sizes, int n_in,
                              void* d_out, int out_size, void* d_ws, size_t ws_size,
                              hipStream_t stream) {
    const float* x    = (const float*)d_in[0];
    const float* pos0 = (const float*)d_in[1];
    const int*   ei   = (const int*)d_in[2];
    const float* W1 = (const float*)d_in[4];  const float* b1 = (const float*)d_in[5];
    const float* W2 = (const float*)d_in[6];  const float* b2 = (const float*)d_in[7];
    const float* W3 = (const float*)d_in[8];  const float* b3 = (const float*)d_in[9];
    const float* W4 = (const float*)d_in[10]; const float* b4 = (const float*)d_in[11];
    const float* W5 = (const float*)d_in[12]; const float* b5 = (const float*)d_in[13];
    const float* Wl1 = (const float*)d_in[14]; const float* bl1 = (const float*)d_in[15];
    const float* Wl2 = (const float*)d_in[16]; const float* bl2 = (const float*)d_in[17];
    const int* src0 = ei;
    const int* dst0 = ei + NE;
    float* out = (float*)d_out;

    float* w = (float*)d_ws;
    size_t off = 0;
    auto alloc = [&](size_t n) { float* p = w + off; off += n; return p; };

    // --- zero-init region (pool accumulators), contiguous: one memset ---
    float* hp1   = alloc((size_t)N1 * 16);
    float* psum1 = alloc((size_t)N1 * 3);
    float* cnt1  = alloc(N1);
    float* hp2   = alloc((size_t)N2 * 32);
    float* psum2 = alloc((size_t)N2 * 3);
    float* cnt2  = alloc(N2);
    float* g     = alloc((size_t)B_GRAPHS * 4096);
    float* hid   = alloc((size_t)B_GRAPHS * 1024);
    size_t zero_bytes = off * sizeof(float);
    // --- rest (fully overwritten before use) ---
    float* abuf = alloc((size_t)N_NODES * 16);
    float* h2   = alloc((size_t)N1 * 32);
    float* h4   = alloc((size_t)N2 * 64);
    float* pos1 = alloc((size_t)N1 * 3);
    float* pos2 = alloc((size_t)N2 * 3);
    int* c1     = (int*)alloc(N_NODES);
    int* c2     = (int*)alloc(N1);
    int* s1     = (int*)alloc(NE);
    int* d1     = (int*)alloc(NE);
    int* counts  = (int*)alloc(N_NODES + 2);
    int* offsets = (int*)alloc(N_NODES + 2);
    int* cursor  = (int*)alloc(N_NODES + 2);
    int* csr_src = (int*)alloc(NE);
    int* blocksums = (int*)alloc(512);
    int* blockpref = (int*)alloc(512);
    (void)ws_size; (void)in_sizes; (void)n_in; (void)out_size;

    hipMemsetAsync(d_ws, 0, zero_bytes, stream);

    const int eblocks = NE / 256;
    auto csr_scan = [&](int n) {
        scan_reduce_kernel<<<n / 1024, 256, 0, stream>>>(counts, blocksums);
        scan_blocks_kernel<<<1, 256, 0, stream>>>(blocksums, blockpref, offsets, n / 1024, n);
        scan_write_kernel<<<n / 1024, 256, 0, stream>>>(counts, blockpref, offsets, cursor);
    };

    // ===== level A: conv1 on raw events, fused pool1 h-max =====
    node_a_kernel<1, 16><<<N_NODES / 256, 256, 0, stream>>>(x, pos0, W1, b1, abuf, N_NODES);
    hipMemsetAsync(counts, 0, N_NODES * sizeof(int), stream);
    count_kernel<<<eblocks, 256, 0, stream>>>(dst0, counts, NE, N_NODES);
    csr_scan(N_NODES);
    fill_kernel<<<eblocks, 256, 0, stream>>>(src0, dst0, cursor, csr_src, NE, N_NODES);
    cluster_kernel<<<N_NODES / 256, 256, 0, stream>>>(pos0, c1, psum1, cnt1, N_NODES, 13, 0.25f, 32);
    gather_kernel<16, 1><<<N_NODES / 4, 256, 0, stream>>>(abuf, pos0, W1 + 1 * 16,
                                                          offsets, csr_src, c1, hp1, N_NODES);
    posfin_kernel<<<N1 / 256, 256, 0, stream>>>(psum1, cnt1, pos1, N1);
    hipMemsetAsync(counts, 0, N1 * sizeof(int), stream);
    remap_count_kernel<<<eblocks, 256, 0, stream>>>(src0, dst0, c1, s1, d1, counts, NE, N_NODES, N1);

    // ===== level B: conv2 (store), conv3 (fused pool2 h-max) =====
    csr_scan(N1);
    fill_kernel<<<eblocks, 256, 0, stream>>>(s1, d1, cursor, csr_src, NE, N1);
    node_a_kernel<16, 32><<<N1 / 256, 256, 0, stream>>>(hp1, pos1, W2, b2, abuf, N1);
    gather_kernel<32, 0><<<N1 / 4, 256, 0, stream>>>(abuf, pos1, W2 + 16 * 32,
                                                     offsets, csr_src, nullptr, h2, N1);
    node_a_kernel<32, 32><<<N1 / 256, 256, 0, stream>>>(h2, pos1, W3, b3, abuf, N1);
    cluster_kernel<<<N1 / 256, 256, 0, stream>>>(pos1, c2, psum2, cnt2, N1, 10, 0.125f, 16);
    gather_kernel<32, 1><<<N1 / 4, 256, 0, stream>>>(abuf, pos1, W3 + 32 * 32,
                                                     offsets, csr_src, c2, hp2, N1);
    posfin_kernel<<<N2 / 256, 256, 0, stream>>>(psum2, cnt2, pos2, N2);
    hipMemsetAsync(counts, 0, N2 * sizeof(int), stream);
    remap_count_kernel<<<eblocks, 256, 0, stream>>>(s1, d1, c2, s1, d1, counts, NE, N1, N2);

    // ===== level C: conv4 (store), conv5 (fused pool_out) =====
    csr_scan(N2);
    fill_kernel<<<eblocks, 256, 0, stream>>>(s1, d1, cursor, csr_src, NE, N2);
    node_a_kernel<32, 64><<<N2 / 256, 256, 0, stream>>>(hp2, pos2, W4, b4, abuf, N2);
    gather_kernel<64, 0><<<N2 / 4, 256, 0, stream>>>(abuf, pos2, W4 + 32 * 64,
                                                     offsets, csr_src, nullptr, h4, N2);
    node_a_kernel<64, 64><<<N2 / 256, 256, 0, stream>>>(h4, pos2, W5, b5, abuf, N2);
    cellout_kernel<<<N2 / 256, 256, 0, stream>>>(pos2, c2, N2);
    gather_kernel<64, 1><<<N2 / 4, 256, 0, stream>>>(abuf, pos2, W5 + 64 * 64,
                                                     offsets, csr_src, c2, g, N2);

    // ===== MLP head =====
    mlp1_kernel<<<dim3(32, 8), 256, 0, stream>>>(g, Wl1, hid);
    mlp2_kernel<<<32, 64, 0, stream>>>(hid, bl1, Wl2, bl2, out);
}

// Round 4
// 949.624 us; speedup vs baseline: 18.9678x; 1.3616x over previous
//
#include <hip/hip_runtime.h>
#include <cstdint>
#include <cstddef>

#define B_GRAPHS 32
#define NPG      8192
#define N_NODES  (B_GRAPHS * NPG)   // 262144
#define DEG      8
#define NE       (N_NODES * DEG)    // 2097152
#define N1       32768              // B * 32*32  (grid 4)
#define N2       8192               // B * 16*16  (grid 8)
#define BKT_CAP  80

// ---------------------------------------------------------------------------
// Node-level precompute: a[i,o] = b[o] + sum_k h[i,k]*W[k,o] + px*W[IN,o] + py*W[IN+1,o]
// ---------------------------------------------------------------------------
template<int IN, int OUT>
__global__ __launch_bounds__(256)
void node_a_kernel(const float* __restrict__ h, const float* __restrict__ pos,
                   const float* __restrict__ W, const float* __restrict__ bias,
                   float* __restrict__ a, int n) {
    constexpr int FEAT = IN + 2;
    __shared__ float Ws[FEAT * OUT + OUT];
    for (int i = threadIdx.x; i < FEAT * OUT; i += 256) Ws[i] = W[i];
    for (int i = threadIdx.x; i < OUT; i += 256) Ws[FEAT * OUT + i] = bias[i];
    __syncthreads();
    int i = blockIdx.x * 256 + threadIdx.x;
    if (i >= n) return;

    float acc[OUT];
    #pragma unroll
    for (int o = 0; o < OUT; ++o) acc[o] = Ws[FEAT * OUT + o];

    float px = pos[i * 3 + 0], py = pos[i * 3 + 1];
    #pragma unroll
    for (int o = 0; o < OUT; ++o)
        acc[o] += px * Ws[IN * OUT + o] + py * Ws[(IN + 1) * OUT + o];

    if constexpr (IN % 4 == 0) {
        const float4* h4 = (const float4*)(h + (size_t)i * IN);
        for (int k4 = 0; k4 < IN / 4; ++k4) {
            float4 f = h4[k4];
            #pragma unroll
            for (int o = 0; o < OUT; ++o) {
                acc[o] += f.x * Ws[(k4 * 4 + 0) * OUT + o];
                acc[o] += f.y * Ws[(k4 * 4 + 1) * OUT + o];
                acc[o] += f.z * Ws[(k4 * 4 + 2) * OUT + o];
                acc[o] += f.w * Ws[(k4 * 4 + 3) * OUT + o];
            }
        }
    } else {
        for (int k = 0; k < IN; ++k) {
            float f = h[(size_t)i * IN + k];
            #pragma unroll
            for (int o = 0; o < OUT; ++o) acc[o] += f * Ws[k * OUT + o];
        }
    }
    float* ap = a + (size_t)i * OUT;
    #pragma unroll
    for (int o = 0; o < OUT; ++o) ap[o] = acc[o];
}

// ---------------------------------------------------------------------------
// Per-graph edge histogram (gcnt must be zeroed).
// ---------------------------------------------------------------------------
__global__ __launch_bounds__(256)
void precount_kernel(const int* __restrict__ dst, int* __restrict__ gcnt) {
    __shared__ int hist[B_GRAPHS];
    if (threadIdx.x < B_GRAPHS) hist[threadIdx.x] = 0;
    __syncthreads();
    int gid = blockIdx.x * 256 + threadIdx.x;
    for (int e = gid; e < NE; e += 256 * 256)
        atomicAdd(&hist[dst[e] >> 13], 1);
    __syncthreads();
    if (threadIdx.x < B_GRAPHS) atomicAdd(&gcnt[threadIdx.x], hist[threadIdx.x]);
}

__global__ void gscan_kernel(const int* __restrict__ gcnt, int* __restrict__ gbase,
                             int* __restrict__ gcur) {
    if (threadIdx.x == 0) {
        int run = 0;
        for (int g = 0; g < B_GRAPHS; ++g) {
            gbase[g] = run; gcur[g] = run;
            run += gcnt[g];
        }
        gbase[B_GRAPHS] = run;
    }
}

// ---------------------------------------------------------------------------
// Bucket edges by graph into graph-major (src,dst) pairs. Coalesced flushes.
// ---------------------------------------------------------------------------
__global__ __launch_bounds__(256)
void bucket_kernel(const int* __restrict__ src, const int* __restrict__ dst,
                   int* __restrict__ gcur, int2* __restrict__ binned) {
    __shared__ int2 bins[B_GRAPHS][BKT_CAP];
    __shared__ int bcnt[B_GRAPHS], sbase[B_GRAPHS], sn[B_GRAPHS];
    int tid = threadIdx.x;
    if (tid < B_GRAPHS) bcnt[tid] = 0;
    __syncthreads();
    int wgbase = blockIdx.x * 2048;
    for (int sub = 0; sub < 2; ++sub) {
        int e0 = wgbase + sub * 1024 + tid * 4;
        int4 s4 = *(const int4*)&src[e0];
        int4 d4 = *(const int4*)&dst[e0];
        int ss[4] = {s4.x, s4.y, s4.z, s4.w};
        int dd[4] = {d4.x, d4.y, d4.z, d4.w};
        #pragma unroll
        for (int k = 0; k < 4; ++k) {
            int b = dd[k] >> 13;
            int pos = atomicAdd(&bcnt[b], 1);
            if (pos < BKT_CAP) bins[b][pos] = make_int2(ss[k], dd[k]);
            else { int gp = atomicAdd(&gcur[b], 1); binned[gp] = make_int2(ss[k], dd[k]); }
        }
        __syncthreads();
        if (tid < B_GRAPHS) {
            int nb = min(bcnt[tid], BKT_CAP);
            sn[tid] = nb;
            sbase[tid] = atomicAdd(&gcur[tid], nb);
        }
        __syncthreads();
        int b = tid >> 3, r = tid & 7;
        for (int k = r; k < sn[b]; k += 8) binned[sbase[b] + k] = bins[b][k];
        __syncthreads();
        if (tid < B_GRAPHS) bcnt[tid] = 0;
        __syncthreads();
    }
}

// ---------------------------------------------------------------------------
// Per-graph CSR build at level A: count -> LDS scan -> fill. One wg per graph:
// all csr writes stay in one XCD's L2 (no cross-XCD line thrash).
// ---------------------------------------------------------------------------
__global__ __launch_bounds__(1024)
void csrA_kernel(const int2* __restrict__ binned, const int* __restrict__ gbase,
                 const int* __restrict__ gend,
                 int* __restrict__ lo, int* __restrict__ hi, int* __restrict__ csr) {
    __shared__ int cnt[NPG];
    __shared__ int aux[1024];
    int g = blockIdx.x, t = threadIdx.x;
    for (int i = t; i < NPG; i += 1024) cnt[i] = 0;
    __syncthreads();
    int segb = gbase[g], sege = gend[g];
    int nodeb = g * NPG;
    for (int e = segb + t; e < sege; e += 1024)
        atomicAdd(&cnt[binned[e].y - nodeb], 1);
    __syncthreads();
    int c[8], sum = 0;
    #pragma unroll
    for (int k = 0; k < 8; ++k) { c[k] = cnt[t * 8 + k]; sum += c[k]; }
    aux[t] = sum;
    __syncthreads();
    for (int d = 1; d < 1024; d <<= 1) {
        int v = (t >= d) ? aux[t - d] : 0;
        __syncthreads();
        aux[t] += v;
        __syncthreads();
    }
    int run = segb + aux[t] - sum;
    #pragma unroll
    for (int k = 0; k < 8; ++k) {
        int i = nodeb + t * 8 + k;
        lo[i] = run; hi[i] = run + c[k];
        cnt[t * 8 + k] = run;
        run += c[k];
    }
    __syncthreads();
    for (int e = segb + t; e < sege; e += 1024) {
        int2 sd = binned[e];
        int p = atomicAdd(&cnt[sd.y - nodeb], 1);
        csr[p] = sd.x;
    }
}

// ---------------------------------------------------------------------------
// Per-graph CSR for the next level: fused remap (cluster) + self-loop drop +
// count + scan + fill. Capacity per graph: valid_next <= edges_A -> reuse gbase.
// ---------------------------------------------------------------------------
template<int OLDPG, int NEWPG>
__global__ __launch_bounds__(1024)
void csr_next_kernel(const int* __restrict__ lo_o, const int* __restrict__ hi_o,
                     const int* __restrict__ csr_o, const int* __restrict__ cl,
                     const int* __restrict__ gbase,
                     int* __restrict__ lo_n, int* __restrict__ hi_n,
                     int* __restrict__ csr_n) {
    __shared__ int cnt[NEWPG];
    int g = blockIdx.x, t = threadIdx.x;
    int nodeb = g * OLDPG, clb = g * NEWPG;
    for (int i = t; i < NEWPG; i += 1024) cnt[i] = 0;
    __syncthreads();
    for (int local = t; local < OLDPG; local += 1024) {
        int i = nodeb + local;
        int dB = cl[i];
        int l = lo_o[i], h = hi_o[i];
        int acc = 0;
        for (int j = l; j < h; ++j)
            if (cl[csr_o[j]] != dB) ++acc;
        if (acc) atomicAdd(&cnt[dB - clb], acc);
    }
    __syncthreads();
    int myc = (t < NEWPG) ? cnt[t] : 0;
    for (int d = 1; d < NEWPG; d <<= 1) {
        int v = (t >= d && t < NEWPG) ? cnt[t - d] : 0;
        __syncthreads();
        if (t < NEWPG) cnt[t] += v;
        __syncthreads();
    }
    int start = 0;
    if (t < NEWPG) {
        start = gbase[g] + cnt[t] - myc;
        lo_n[clb + t] = start;
        hi_n[clb + t] = start + myc;
    }
    __syncthreads();
    if (t < NEWPG) cnt[t] = start;
    __syncthreads();
    for (int local = t; local < OLDPG; local += 1024) {
        int i = nodeb + local;
        int dB = cl[i];
        int l = lo_o[i], h = hi_o[i];
        for (int j = l; j < h; ++j) {
            int sB = cl[csr_o[j]];
            if (sB != dB) {
                int p = atomicAdd(&cnt[dB - clb], 1);
                csr_n[p] = sB;
            }
        }
    }
}

// ---------------------------------------------------------------------------
// Gather-max conv, wave per node (for small OUT / small degree).
// MODE 0: store per-node; MODE 1: atomicMax into out[cluster[node]] (>=0, 0-init)
// ---------------------------------------------------------------------------
template<int OUT, int MODE>
__global__ __launch_bounds__(256)
void gatherw_kernel(const float* __restrict__ a, const float* __restrict__ pos,
                    const float* __restrict__ Wp,
                    const int* __restrict__ lo, const int* __restrict__ hi,
                    const int* __restrict__ csr, const int* __restrict__ cluster,
                    float* __restrict__ out, int n) {
    constexpr int G = 64 / OUT;
    int wave = (blockIdx.x * 256 + threadIdx.x) >> 6;
    int lane = threadIdx.x & 63;
    int ch = lane % OUT, grp = lane / OUT;
    if (wave >= n) return;
    int l = lo[wave], h = hi[wave];
    float m = -1e30f;
    for (int j = l + grp; j < h; j += G)
        m = fmaxf(m, a[(size_t)csr[j] * OUT + ch]);
    #pragma unroll
    for (int st = OUT; st < 64; st <<= 1)
        m = fmaxf(m, __shfl_xor(m, st, 64));
    float px = pos[wave * 3 + 0], py = pos[wave * 3 + 1];
    float cterm = px * Wp[ch] + py * Wp[OUT + ch];
    float val = (h > l) ? fmaxf(m - cterm, 0.0f) : 0.0f;
    if (grp == 0) {
        if (MODE == 0) out[(size_t)wave * OUT + ch] = val;
        else if (val > 0.0f)
            atomicMax((int*)&out[(size_t)cluster[wave] * OUT + ch], __float_as_int(val));
    }
}

// Block(256) per node, 256/OUT slot-streams, LDS max-combine (for big degree).
template<int OUT, int MODE>
__global__ __launch_bounds__(256)
void gather4_kernel(const float* __restrict__ a, const float* __restrict__ pos,
                    const float* __restrict__ Wp,
                    const int* __restrict__ lo, const int* __restrict__ hi,
                    const int* __restrict__ csr, const int* __restrict__ cluster,
                    float* __restrict__ out) {
    constexpr int STREAMS = 256 / OUT;
    int node = blockIdx.x;
    int tid = threadIdx.x;
    int ch = tid % OUT, s = tid / OUT;
    int l = lo[node], h = hi[node];
    float m = -1e30f;
    for (int j = l + s; j < h; j += STREAMS)
        m = fmaxf(m, a[(size_t)csr[j] * OUT + ch]);
    __shared__ float sh[256];
    sh[tid] = m;
    __syncthreads();
    if (tid < OUT) {
        #pragma unroll
        for (int k = 1; k < STREAMS; ++k) m = fmaxf(m, sh[k * OUT + tid]);
        float px = pos[node * 3 + 0], py = pos[node * 3 + 1];
        float cterm = px * Wp[tid] + py * Wp[OUT + tid];
        float val = (h > l) ? fmaxf(m - cterm, 0.0f) : 0.0f;
        if (MODE == 0) out[(size_t)node * OUT + tid] = val;
        else if (val > 0.0f)
            atomicMax((int*)&out[(size_t)cluster[node] * OUT + tid], __float_as_int(val));
    }
}

// ---------------------------------------------------------------------------
// Voxel cluster id + pos mean accumulation; pos finalize; out-cell ids
// ---------------------------------------------------------------------------
__global__ __launch_bounds__(256)
void cluster_kernel(const float* __restrict__ pos, int* __restrict__ cluster,
                    float* __restrict__ psum, float* __restrict__ cnt,
                    int n, int batch_shift, float inv_grid, int cells) {
    int i = blockIdx.x * 256 + threadIdx.x;
    if (i >= n) return;
    float px = pos[i * 3 + 0], py = pos[i * 3 + 1], pz = pos[i * 3 + 2];
    int ix = min(max((int)floorf(px * inv_grid), 0), cells - 1);
    int iy = min(max((int)floorf(py * inv_grid), 0), cells - 1);
    int c = (i >> batch_shift) * cells * cells + iy * cells + ix;
    cluster[i] = c;
    atomicAdd(&psum[c * 3 + 0], px);
    atomicAdd(&psum[c * 3 + 1], py);
    atomicAdd(&psum[c * 3 + 2], pz);
    atomicAdd(&cnt[c], 1.0f);
}

__global__ __launch_bounds__(256)
void posfin_kernel(const float* __restrict__ pos_sum, const float* __restrict__ cnt,
                   float* __restrict__ pos_new, int n_new) {
    int i = blockIdx.x * 256 + threadIdx.x;
    if (i >= n_new) return;
    float c = fmaxf(cnt[i], 1.0f);
    pos_new[i * 3 + 0] = pos_sum[i * 3 + 0] / c;
    pos_new[i * 3 + 1] = pos_sum[i * 3 + 1] / c;
    pos_new[i * 3 + 2] = pos_sum[i * 3 + 2] / c;
}

__global__ __launch_bounds__(256)
void cellout_kernel(const float* __restrict__ pos, int* __restrict__ cell, int n) {
    int i = blockIdx.x * 256 + threadIdx.x;
    if (i >= n) return;
    float px = pos[i * 3 + 0], py = pos[i * 3 + 1];
    int ix = min(max((int)floorf(px * (1.0f / 16.0f)), 0), 7);
    int iy = min(max((int)floorf(py * (1.0f / 16.0f)), 0), 7);
    cell[i] = (i >> 8) * 64 + iy * 8 + ix;
}

// ---------------------------------------------------------------------------
// MLP head
// ---------------------------------------------------------------------------
__global__ __launch_bounds__(256)
void mlp1_kernel(const float* __restrict__ g, const float* __restrict__ Wl1,
                 float* __restrict__ hid) {
    int b = blockIdx.x, kc = blockIdx.y, t = threadIdx.x;
    const float* grow = g + (size_t)b * 4096;
    int o0 = t * 4;
    float a0 = 0, a1 = 0, a2 = 0, a3 = 0;
    int k0 = kc * 512;
    for (int k = k0; k < k0 + 512; ++k) {
        float gk = grow[k];
        float4 w = *(const float4*)&Wl1[(size_t)k * 1024 + o0];
        a0 += gk * w.x; a1 += gk * w.y; a2 += gk * w.z; a3 += gk * w.w;
    }
    float* hp = hid + (size_t)b * 1024 + o0;
    atomicAdd(hp + 0, a0);
    atomicAdd(hp + 1, a1);
    atomicAdd(hp + 2, a2);
    atomicAdd(hp + 3, a3);
}

__global__ __launch_bounds__(64)
void mlp2_kernel(const float* __restrict__ hid, const float* __restrict__ bl1,
                 const float* __restrict__ Wl2, const float* __restrict__ bl2,
                 float* __restrict__ out) {
    int b = blockIdx.x, l = threadIdx.x;
    float hv[16];
    #pragma unroll
    for (int i = 0; i < 16; ++i) {
        int idx = l + i * 64;
        hv[i] = fmaxf(hid[(size_t)b * 1024 + idx] + bl1[idx], 0.0f);
    }
    float logits[10];
    #pragma unroll
    for (int c = 0; c < 10; ++c) {
        float p = 0.0f;
        #pragma unroll
        for (int i = 0; i < 16; ++i)
            p += hv[i] * Wl2[(size_t)(l + i * 64) * 10 + c];
        #pragma unroll
        for (int off = 32; off > 0; off >>= 1) p += __shfl_xor(p, off, 64);
        logits[c] = p + bl2[c];
    }
    float m = logits[0];
    #pragma unroll
    for (int c = 1; c < 10; ++c) m = fmaxf(m, logits[c]);
    float ssum = 0.0f;
    #pragma unroll
    for (int c = 0; c < 10; ++c) ssum += expf(logits[c] - m);
    float lse = logf(ssum);
    if (l < 10) out[b * 10 + l] = logits[l] - m - lse;
}

// ---------------------------------------------------------------------------
extern "C" void kernel_launch(void* const* d_in, const int* in_sizes, int n_in,
                              void* d_out, int out_size, void* d_ws, size_t ws_size,
                              hipStream_t stream) {
    const float* x    = (const float*)d_in[0];
    const float* pos0 = (const float*)d_in[1];
    const int*   ei   = (const int*)d_in[2];
    const float* W1 = (const float*)d_in[4];  const float* b1 = (const float*)d_in[5];
    const float* W2 = (const float*)d_in[6];  const float* b2 = (const float*)d_in[7];
    const float* W3 = (const float*)d_in[8];  const float* b3 = (const float*)d_in[9];
    const float* W4 = (const float*)d_in[10]; const float* b4 = (const float*)d_in[11];
    const float* W5 = (const float*)d_in[12]; const float* b5 = (const float*)d_in[13];
    const float* Wl1 = (const float*)d_in[14]; const float* bl1 = (const float*)d_in[15];
    const float* Wl2 = (const float*)d_in[16]; const float* bl2 = (const float*)d_in[17];
    const int* src0 = ei;
    const int* dst0 = ei + NE;
    float* out = (float*)d_out;

    float* w = (float*)d_ws;
    size_t off = 0;
    auto alloc = [&](size_t n) { float* p = w + off; off += n; return p; };

    // --- zero-init region (one memset) ---
    int*   gcnt  = (int*)alloc(32);
    float* hp1   = alloc((size_t)N1 * 16);
    float* psum1 = alloc((size_t)N1 * 3);
    float* cnt1  = alloc(N1);
    float* hp2   = alloc((size_t)N2 * 32);
    float* psum2 = alloc((size_t)N2 * 3);
    float* cnt2  = alloc(N2);
    float* g     = alloc((size_t)B_GRAPHS * 4096);
    float* hid   = alloc((size_t)B_GRAPHS * 1024);
    size_t zero_bytes = off * sizeof(float);
    // --- abuf ---
    float* abuf = alloc((size_t)N_NODES * 16);
    // --- union: binned (level A only) overlaps {csr1, h2, h4, pos2, cell} ---
    float* ubase = alloc((size_t)NE * 2);     // 4M floats
    int2*  binned = (int2*)ubase;
    int*   csr1 = (int*)ubase;                              // NE
    float* h2   = ubase + (size_t)NE;                       // N1*32 = 1M
    float* h4   = h2 + (size_t)N1 * 32;                     // N2*64 = 0.5M
    float* pos2 = h4 + (size_t)N2 * 64;                     // N2*3
    int*   cell = (int*)(pos2 + (size_t)N2 * 3);            // N2
    // --- rest ---
    int* csr0 = (int*)alloc(NE);
    int* loA  = (int*)alloc(N_NODES);
    int* hiA  = (int*)alloc(N_NODES);
    int* loB  = (int*)alloc(N1);
    int* hiB  = (int*)alloc(N1);
    int* loC  = (int*)alloc(N2);
    int* hiC  = (int*)alloc(N2);
    float* pos1 = alloc((size_t)N1 * 3);
    int* c1   = (int*)alloc(N_NODES);
    int* c2   = (int*)alloc(N1);
    int* gbase = (int*)alloc(64);
    int* gcur  = (int*)alloc(64);
    (void)ws_size; (void)in_sizes; (void)n_in; (void)out_size;

    hipMemsetAsync(d_ws, 0, zero_bytes, stream);

    // ===== level A =====
    node_a_kernel<1, 16><<<N_NODES / 256, 256, 0, stream>>>(x, pos0, W1, b1, abuf, N_NODES);
    precount_kernel<<<256, 256, 0, stream>>>(dst0, gcnt);
    gscan_kernel<<<1, 64, 0, stream>>>(gcnt, gbase, gcur);
    bucket_kernel<<<NE / 2048, 256, 0, stream>>>(src0, dst0, gcur, binned);
    csrA_kernel<<<B_GRAPHS, 1024, 0, stream>>>(binned, gbase, gcur, loA, hiA, csr0);
    cluster_kernel<<<N_NODES / 256, 256, 0, stream>>>(pos0, c1, psum1, cnt1, N_NODES, 13, 0.25f, 32);
    gatherw_kernel<16, 1><<<N_NODES / 4, 256, 0, stream>>>(abuf, pos0, W1 + 16,
                                                           loA, hiA, csr0, c1, hp1, N_NODES);
    posfin_kernel<<<N1 / 256, 256, 0, stream>>>(psum1, cnt1, pos1, N1);

    // ===== level B (CSR-B fuses remap+count+scan+fill; binned is dead now) =====
    csr_next_kernel<NPG, 1024><<<B_GRAPHS, 1024, 0, stream>>>(loA, hiA, csr0, c1, gbase,
                                                              loB, hiB, csr1);
    node_a_kernel<16, 32><<<N1 / 256, 256, 0, stream>>>(hp1, pos1, W2, b2, abuf, N1);
    gather4_kernel<32, 0><<<N1, 256, 0, stream>>>(abuf, pos1, W2 + 512,
                                                  loB, hiB, csr1, nullptr, h2);
    node_a_kernel<32, 32><<<N1 / 256, 256, 0, stream>>>(h2, pos1, W3, b3, abuf, N1);
    cluster_kernel<<<N1 / 256, 256, 0, stream>>>(pos1, c2, psum2, cnt2, N1, 10, 0.125f, 16);
    gather4_kernel<32, 1><<<N1, 256, 0, stream>>>(abuf, pos1, W3 + 1024,
                                                  loB, hiB, csr1, c2, hp2);
    posfin_kernel<<<N2 / 256, 256, 0, stream>>>(psum2, cnt2, pos2, N2);

    // ===== level C =====
    csr_next_kernel<1024, 256><<<B_GRAPHS, 1024, 0, stream>>>(loB, hiB, csr1, c2, gbase,
                                                              loC, hiC, csr0);
    node_a_kernel<32, 64><<<N2 / 256, 256, 0, stream>>>(hp2, pos2, W4, b4, abuf, N2);
    gather4_kernel<64, 0><<<N2, 256, 0, stream>>>(abuf, pos2, W4 + 2048,
                                                  loC, hiC, csr0, nullptr, h4);
    node_a_kernel<64, 64><<<N2 / 256, 256, 0, stream>>>(h4, pos2, W5, b5, abuf, N2);
    cellout_kernel<<<N2 / 256, 256, 0, stream>>>(pos2, cell, N2);
    gather4_kernel<64, 1><<<N2, 256, 0, stream>>>(abuf, pos2, W5 + 4096,
                                                  loC, hiC, csr0, cell, g);

    // ===== MLP head =====
    mlp1_kernel<<<dim3(32, 8), 256, 0, stream>>>(g, Wl1, hid);
    mlp2_kernel<<<32, 64, 0, stream>>>(hid, bl1, Wl2, bl2, out);
}